// Round 10
// baseline (1197.366 us; speedup 1.0000x reference)
//
#include <hip/hip_runtime.h>
#include <hip/hip_cooperative_groups.h>
#include <cstdint>

namespace cg = cooperative_groups;

#define HN 64
#define HE 64
#define NNODE 50000
#define NEDGE 200000
#define NTRIP 600000
#define EPSBN 1e-5f

#define NB3 ((NTRIP + 127) / 128)   // 4688 c3 tiles
#define NB2 ((NEDGE + 127) / 128)   // 1563 c2 tiles

// gstats (floats): c2_sum(128) c2_sq(128) c3_sum(128) c3_sq(128)
//                  u_sum(64) u_sq(64) agg_sum(64) agg_sq(64) = 768
// scales (floats): c2_scale(128) c2_shift(128) c3_scale(128) c3_shift(128)
//                  u_scale(64) u_shift(64) agg_scale(64) agg_shift(64) = 768

typedef __attribute__((ext_vector_type(8))) short short8;
typedef __attribute__((ext_vector_type(4))) float f32x4;

__device__ __forceinline__ float sigmoid_f(float x) {
    return 1.0f / (1.0f + __expf(-x));
}
__device__ __forceinline__ float tanh_f(float x) {
    return 1.0f - 2.0f / (__expf(2.0f * x) + 1.0f);
}
__device__ __forceinline__ short8 as_s8(uint4 v) {
    union { uint4 u; short8 s; } c; c.u = v; return c.s;
}

__device__ __forceinline__ void cvt_store16(
    float4 x0, float4 x1, float4 x2, float4 x3,
    unsigned int* __restrict__ dhi, unsigned int* __restrict__ dlo, bool do_lo)
{
    float xv[16] = {x0.x, x0.y, x0.z, x0.w, x1.x, x1.y, x1.z, x1.w,
                    x2.x, x2.y, x2.z, x2.w, x3.x, x3.y, x3.z, x3.w};
    unsigned hu[16];
#pragma unroll
    for (int e = 0; e < 16; ++e) hu[e] = __float_as_uint(xv[e]) >> 16;  // truncate split
#pragma unroll
    for (int m = 0; m < 8; ++m) dhi[m] = (hu[2 * m + 1] << 16) | hu[2 * m];
    if (do_lo) {
        unsigned lu[16];
#pragma unroll
        for (int e = 0; e < 16; ++e) {
            const float hf = __uint_as_float(hu[e] << 16);
            lu[e] = __float_as_uint(xv[e] - hf) >> 16;  // exact residual
        }
#pragma unroll
        for (int m = 0; m < 8; ++m) dlo[m] = (lu[2 * m + 1] << 16) | lu[2 * m];
    }
}

// ---------------------------------------------------------------------------
// Tile bodies (byte-identical math to r8's proven kernels), shared between
// the cooperative mega-kernel and the r8-fallback standalone kernels.
// smem layout: sA = smem[0..5119], sB = smem[5120..10239],
//              sstat = (float*)&smem[10240] (256 floats) -> 41984 B total.
// ---------------------------------------------------------------------------
template <int TERMS>
__device__ __forceinline__ void c3_tile(
    int bt, const float* __restrict__ node, const float* __restrict__ edge,
    const int* __restrict__ idx_i, const int* __restrict__ idx_j,
    const int* __restrict__ idx_k, const int* __restrict__ idx_ji,
    const int* __restrict__ idx_kj, const float* __restrict__ W3,
    float* __restrict__ gstats, const float* __restrict__ scales,
    float* __restrict__ agg, unsigned* __restrict__ smem)
{
    constexpr int LDA = 20;
    constexpr int PLANE = 128 * LDA;  // 2560
    unsigned* sA = smem;
    unsigned* sB = smem + 2 * PLANE;
    float* sstat = reinterpret_cast<float*>(smem + 4 * PLANE);

    const int tid = threadIdx.x;
    const int lane = tid & 63;
    const int w = tid >> 6;
    const int quad = lane >> 4;
    const int l16 = lane & 15;
    const int bm = bt * 128;

    const int srow = tid >> 1;
    const int shalf = tid & 1;
    int g = bm + srow;
    if (g >= NTRIP) g = NTRIP - 1;
    const int r0 = idx_i[g], r1 = idx_j[g], r2 = idx_k[g];
    const int r3 = idx_ji[g], r4 = idx_kj[g];

    f32x4 acc[2][8];
#pragma unroll
    for (int mi = 0; mi < 2; ++mi)
#pragma unroll
        for (int ni = 0; ni < 8; ++ni) acc[mi][ni] = (f32x4){0.f, 0.f, 0.f, 0.f};

    for (int s = 0; s < 10; ++s) {
        const int seg = s >> 1;
        const int kin = (s & 1) * 32;
        const float* src;
        switch (seg) {
            case 0: src = node + (size_t)r0 * 64; break;
            case 1: src = node + (size_t)r1 * 64; break;
            case 2: src = node + (size_t)r2 * 64; break;
            case 3: src = edge + (size_t)r3 * 64; break;
            default: src = edge + (size_t)r4 * 64; break;
        }
        const float4* pa = reinterpret_cast<const float4*>(src + kin + shalf * 16);
        float4 a0 = pa[0], a1 = pa[1], a2 = pa[2], a3 = pa[3];
        const float4* pb = reinterpret_cast<const float4*>(
            W3 + (size_t)srow * 320 + seg * 64 + kin + shalf * 16);
        float4 b0 = pb[0], b1 = pb[1], b2 = pb[2], b3 = pb[3];

        __syncthreads();
        {
            unsigned* dA = sA + srow * LDA + shalf * 8;
            unsigned* dB = sB + srow * LDA + shalf * 8;
            cvt_store16(a0, a1, a2, a3, dA, dA + PLANE, TERMS == 3);
            cvt_store16(b0, b1, b2, b3, dB, dB + PLANE, TERMS == 3);
        }
        __syncthreads();

        uint4 ahi[2], alo[2];
#pragma unroll
        for (int mi = 0; mi < 2; ++mi) {
            const int abase = (w * 32 + mi * 16 + l16) * LDA + quad * 4;
            ahi[mi] = *reinterpret_cast<const uint4*>(&sA[abase]);
            if (TERMS == 3) alo[mi] = *reinterpret_cast<const uint4*>(&sA[PLANE + abase]);
        }
#pragma unroll
        for (int ni = 0; ni < 8; ++ni) {
            const int bbase = (ni * 16 + l16) * LDA + quad * 4;
            const uint4 bhi = *reinterpret_cast<const uint4*>(&sB[bbase]);
#pragma unroll
            for (int mi = 0; mi < 2; ++mi)
                acc[mi][ni] = __builtin_amdgcn_mfma_f32_16x16x32_bf16(
                    as_s8(ahi[mi]), as_s8(bhi), acc[mi][ni], 0, 0, 0);
            if (TERMS == 3) {
                const uint4 blo = *reinterpret_cast<const uint4*>(&sB[PLANE + bbase]);
#pragma unroll
                for (int mi = 0; mi < 2; ++mi) {
                    acc[mi][ni] = __builtin_amdgcn_mfma_f32_16x16x32_bf16(
                        as_s8(ahi[mi]), as_s8(blo), acc[mi][ni], 0, 0, 0);
                    acc[mi][ni] = __builtin_amdgcn_mfma_f32_16x16x32_bf16(
                        as_s8(alo[mi]), as_s8(bhi), acc[mi][ni], 0, 0, 0);
                }
            }
        }
    }

    // C/D: col = ni*16 + l16, row = w*32 + mi*16 + quad*4 + reg
    if constexpr (TERMS == 1) {
        __syncthreads();
        sstat[tid] = 0.0f;
        __syncthreads();
#pragma unroll
        for (int ni = 0; ni < 8; ++ni) {
            const int col = ni * 16 + l16;
            float s = 0.0f, q = 0.0f;
#pragma unroll
            for (int mi = 0; mi < 2; ++mi)
#pragma unroll
                for (int reg = 0; reg < 4; ++reg) {
                    const int grow = bm + w * 32 + mi * 16 + quad * 4 + reg;
                    if (grow < NTRIP) {
                        const float v = acc[mi][ni][reg];
                        s += v; q += v * v;
                    }
                }
            atomicAdd(&sstat[col], s);
            atomicAdd(&sstat[128 + col], q);
        }
        __syncthreads();
        if (tid < 128) {
            atomicAdd(&gstats[256 + tid], sstat[tid]);
            atomicAdd(&gstats[384 + tid], sstat[128 + tid]);
        }
    } else {
        float sf[4], hf[4], sc[4], hc[4];
#pragma unroll
        for (int ni = 0; ni < 4; ++ni) {
            const int col = ni * 16 + l16;
            sf[ni] = scales[256 + col];      hf[ni] = scales[384 + col];
            sc[ni] = scales[256 + 64 + col]; hc[ni] = scales[384 + 64 + col];
        }
#pragma unroll
        for (int mi = 0; mi < 2; ++mi)
#pragma unroll
            for (int reg = 0; reg < 4; ++reg) {
                const int grow = bm + w * 32 + mi * 16 + quad * 4 + reg;
                if (grow < NTRIP) {
                    const int e = idx_ji[grow];
                    float* dst = &agg[(size_t)e * 64 + l16];
#pragma unroll
                    for (int ni = 0; ni < 4; ++ni) {
                        const float fv = acc[mi][ni][reg] * sf[ni] + hf[ni];
                        const float cv = acc[mi][ni + 4][reg] * sc[ni] + hc[ni];
                        atomicAdd(dst + ni * 16, sigmoid_f(fv) * tanh_f(cv));
                    }
                }
            }
    }
}

template <int TERMS>
__device__ __forceinline__ void c2_tile(
    int bt, const float* __restrict__ node, const int* __restrict__ vi,
    const int* __restrict__ vj, const float* __restrict__ W2,
    float* __restrict__ gstats, const float* __restrict__ scales,
    float* __restrict__ uout, unsigned* __restrict__ smem)
{
    constexpr int LDA = 20;
    constexpr int PLANE = 128 * LDA;
    unsigned* sA = smem;
    unsigned* sB = smem + 2 * PLANE;
    float* sstat = reinterpret_cast<float*>(smem + 4 * PLANE);

    const int tid = threadIdx.x;
    const int lane = tid & 63;
    const int w = tid >> 6;
    const int quad = lane >> 4;
    const int l16 = lane & 15;
    const int bm = bt * 128;

    const int srow = tid >> 1;
    const int shalf = tid & 1;
    int g = bm + srow;
    if (g >= NEDGE) g = NEDGE - 1;
    const int r0 = vi[g], r1 = vj[g];

    f32x4 acc[2][8];
#pragma unroll
    for (int mi = 0; mi < 2; ++mi)
#pragma unroll
        for (int ni = 0; ni < 8; ++ni) acc[mi][ni] = (f32x4){0.f, 0.f, 0.f, 0.f};

    for (int s = 0; s < 2; ++s) {
        const int kin = s * 32;
        const float4* pa = reinterpret_cast<const float4*>(
            node + (size_t)r0 * 64 + kin + shalf * 16);
        const float4* pc = reinterpret_cast<const float4*>(
            node + (size_t)r1 * 64 + kin + shalf * 16);
        float4 a0 = pa[0], a1 = pa[1], a2 = pa[2], a3 = pa[3];
        float4 c0 = pc[0], c1 = pc[1], c2 = pc[2], c3 = pc[3];
        float4 m0 = make_float4(a0.x*c0.x, a0.y*c0.y, a0.z*c0.z, a0.w*c0.w);
        float4 m1 = make_float4(a1.x*c1.x, a1.y*c1.y, a1.z*c1.z, a1.w*c1.w);
        float4 m2 = make_float4(a2.x*c2.x, a2.y*c2.y, a2.z*c2.z, a2.w*c2.w);
        float4 m3 = make_float4(a3.x*c3.x, a3.y*c3.y, a3.z*c3.z, a3.w*c3.w);
        const float4* pw = reinterpret_cast<const float4*>(
            W2 + (size_t)srow * 64 + kin + shalf * 16);
        float4 w0 = pw[0], w1 = pw[1], w2 = pw[2], w3 = pw[3];

        __syncthreads();
        {
            unsigned* dA = sA + srow * LDA + shalf * 8;
            unsigned* dB = sB + srow * LDA + shalf * 8;
            cvt_store16(m0, m1, m2, m3, dA, dA + PLANE, TERMS == 3);
            cvt_store16(w0, w1, w2, w3, dB, dB + PLANE, TERMS == 3);
        }
        __syncthreads();

        uint4 ahi[2], alo[2];
#pragma unroll
        for (int mi = 0; mi < 2; ++mi) {
            const int abase = (w * 32 + mi * 16 + l16) * LDA + quad * 4;
            ahi[mi] = *reinterpret_cast<const uint4*>(&sA[abase]);
            if (TERMS == 3) alo[mi] = *reinterpret_cast<const uint4*>(&sA[PLANE + abase]);
        }
#pragma unroll
        for (int ni = 0; ni < 8; ++ni) {
            const int bbase = (ni * 16 + l16) * LDA + quad * 4;
            const uint4 bhi = *reinterpret_cast<const uint4*>(&sB[bbase]);
#pragma unroll
            for (int mi = 0; mi < 2; ++mi)
                acc[mi][ni] = __builtin_amdgcn_mfma_f32_16x16x32_bf16(
                    as_s8(ahi[mi]), as_s8(bhi), acc[mi][ni], 0, 0, 0);
            if (TERMS == 3) {
                const uint4 blo = *reinterpret_cast<const uint4*>(&sB[PLANE + bbase]);
#pragma unroll
                for (int mi = 0; mi < 2; ++mi) {
                    acc[mi][ni] = __builtin_amdgcn_mfma_f32_16x16x32_bf16(
                        as_s8(ahi[mi]), as_s8(blo), acc[mi][ni], 0, 0, 0);
                    acc[mi][ni] = __builtin_amdgcn_mfma_f32_16x16x32_bf16(
                        as_s8(alo[mi]), as_s8(bhi), acc[mi][ni], 0, 0, 0);
                }
            }
        }
    }

    if constexpr (TERMS == 1) {
        __syncthreads();
        sstat[tid] = 0.0f;
        __syncthreads();
#pragma unroll
        for (int ni = 0; ni < 8; ++ni) {
            const int col = ni * 16 + l16;
            float s = 0.0f, q = 0.0f;
#pragma unroll
            for (int mi = 0; mi < 2; ++mi)
#pragma unroll
                for (int reg = 0; reg < 4; ++reg) {
                    const int grow = bm + w * 32 + mi * 16 + quad * 4 + reg;
                    if (grow < NEDGE) {
                        const float v = acc[mi][ni][reg];
                        s += v; q += v * v;
                    }
                }
            atomicAdd(&sstat[col], s);
            atomicAdd(&sstat[128 + col], q);
        }
        __syncthreads();
        if (tid < 128) {
            atomicAdd(&gstats[tid], sstat[tid]);
            atomicAdd(&gstats[128 + tid], sstat[128 + tid]);
        }
    } else {
        float sf[4], hf[4], sc[4], hc[4];
#pragma unroll
        for (int ni = 0; ni < 4; ++ni) {
            const int col = ni * 16 + l16;
            sf[ni] = scales[col];       hf[ni] = scales[128 + col];
            sc[ni] = scales[64 + col];  hc[ni] = scales[192 + col];
        }
        float lsum[4] = {0, 0, 0, 0}, lsq[4] = {0, 0, 0, 0};
#pragma unroll
        for (int mi = 0; mi < 2; ++mi)
#pragma unroll
            for (int reg = 0; reg < 4; ++reg) {
                const int grow = bm + w * 32 + mi * 16 + quad * 4 + reg;
                if (grow < NEDGE) {
#pragma unroll
                    for (int ni = 0; ni < 4; ++ni) {
                        const float f = acc[mi][ni][reg] * sf[ni] + hf[ni];
                        const float c = acc[mi][ni + 4][reg] * sc[ni] + hc[ni];
                        const float uv = sigmoid_f(f) * tanh_f(c);
                        uout[(size_t)grow * 64 + ni * 16 + l16] = uv;
                        lsum[ni] += uv; lsq[ni] += uv * uv;
                    }
                }
            }
        __syncthreads();
        if (tid < 128) sstat[tid] = 0.0f;
        __syncthreads();
#pragma unroll
        for (int ni = 0; ni < 4; ++ni) {
            atomicAdd(&sstat[ni * 16 + l16], lsum[ni]);
            atomicAdd(&sstat[64 + ni * 16 + l16], lsq[ni]);
        }
        __syncthreads();
        if (tid < 64) {
            atomicAdd(&gstats[512 + tid], sstat[tid]);
            atomicAdd(&gstats[576 + tid], sstat[64 + tid]);
        }
    }
}

__device__ __forceinline__ void finalize1_body(
    int t, const float* gstats, const float* g_c2, const float* beta_c2,
    const float* g_c3, const float* beta_c3, float* scales)
{
    if (t < 128) {
        const float inv = 1.0f / (float)NEDGE;
        const float mean = gstats[t] * inv;
        const float var = gstats[128 + t] * inv - mean * mean;
        const float sc = g_c2[t] * rsqrtf(var + EPSBN);
        scales[t] = sc;
        scales[128 + t] = beta_c2[t] - mean * sc;
    } else {
        const int c = t - 128;
        const float inv = 1.0f / (float)NTRIP;
        const float mean = gstats[256 + c] * inv;
        const float var = gstats[384 + c] * inv - mean * mean;
        const float sc = g_c3[c] * rsqrtf(var + EPSBN);
        scales[256 + c] = sc;
        scales[384 + c] = beta_c3[c] - mean * sc;
    }
}

__device__ __forceinline__ void finalize2_body(
    int t, const float* gstats, const float* g_c22, const float* beta_c22,
    const float* g_c32, const float* beta_c32, float* scales)
{
    const float inv = 1.0f / (float)NEDGE;
    if (t < 64) {
        const float mean = gstats[512 + t] * inv;
        const float var = gstats[576 + t] * inv - mean * mean;
        const float sc = g_c22[t] * rsqrtf(var + EPSBN);
        scales[512 + t] = sc;
        scales[576 + t] = beta_c22[t] - mean * sc;
    } else {
        const int c = t - 64;
        const float mean = gstats[640 + c] * inv;
        const float var = gstats[704 + c] * inv - mean * mean;
        const float sc = g_c32[c] * rsqrtf(var + EPSBN);
        scales[640 + c] = sc;
        scales[704 + c] = beta_c32[c] - mean * sc;
    }
}

// ---------------------------------------------------------------------------
// Cooperative mega-kernel: all 6 phases in one dispatch, grid-stride tiles.
// r9 lesson: block-ID fusion gives zero overlap (in-order queue) — only a
// resident grid + grid.sync gives real packing and kills 8 boundaries/tails.
// ---------------------------------------------------------------------------
__global__ __launch_bounds__(256, 3) void k_mega(
    const float* __restrict__ node, const float* __restrict__ edge,
    const int* __restrict__ vi, const int* __restrict__ vj,
    const int* __restrict__ idx_i, const int* __restrict__ idx_j,
    const int* __restrict__ idx_k, const int* __restrict__ idx_ji,
    const int* __restrict__ idx_kj,
    const float* __restrict__ W2, const float* __restrict__ W3,
    const float* __restrict__ g_c2, const float* __restrict__ beta_c2,
    const float* __restrict__ g_c3, const float* __restrict__ beta_c3,
    const float* __restrict__ g_c22, const float* __restrict__ beta_c22,
    const float* __restrict__ g_c32, const float* __restrict__ beta_c32,
    float* __restrict__ gstats, float* __restrict__ scales,
    float* __restrict__ agg, float* __restrict__ out)
{
    __shared__ unsigned smem[4 * 2560 + 256];   // 41984 B
    cg::grid_group grid = cg::this_grid();
    const int tid = threadIdx.x;

    // phase A: stats GEMMs (1-term), c3 + c2 tiles interleaved by grid-stride
    for (int t = blockIdx.x; t < NB3 + NB2; t += gridDim.x) {
        if (t < NB3) c3_tile<1>(t, node, edge, idx_i, idx_j, idx_k, idx_ji,
                                idx_kj, W3, gstats, nullptr, nullptr, smem);
        else        c2_tile<1>(t - NB3, node, vi, vj, W2, gstats, nullptr,
                               nullptr, smem);
    }
    grid.sync();

    if (blockIdx.x == 0)
        finalize1_body(tid, gstats, g_c2, beta_c2, g_c3, beta_c3, scales);
    grid.sync();

    // phase B: apply GEMMs (3-term): c3 -> agg atomics, c2 -> u (out) + stats
    for (int t = blockIdx.x; t < NB3 + NB2; t += gridDim.x) {
        if (t < NB3) c3_tile<3>(t, node, edge, idx_i, idx_j, idx_k, idx_ji,
                                idx_kj, W3, gstats, scales, agg, smem);
        else        c2_tile<3>(t - NB3, node, vi, vj, W2, gstats, scales,
                               out, smem);
    }
    grid.sync();

    // phase C: agg column stats
    {
        const int c4 = tid & 15;
        float ls[4] = {0, 0, 0, 0}, lq[4] = {0, 0, 0, 0};
        const long total = (long)NEDGE * 16;
        const long stride = (long)gridDim.x * 256;
        for (long idx = (long)blockIdx.x * 256 + tid; idx < total; idx += stride) {
            const int row = (int)(idx >> 4);
            const float4 a = *reinterpret_cast<const float4*>(
                &agg[(size_t)row * 64 + c4 * 4]);
            ls[0] += a.x; lq[0] += a.x * a.x;
            ls[1] += a.y; lq[1] += a.y * a.y;
            ls[2] += a.z; lq[2] += a.z * a.z;
            ls[3] += a.w; lq[3] += a.w * a.w;
        }
        float (*red)[16][68] = reinterpret_cast<float(*)[16][68]>(smem);
        __syncthreads();
        const int gr = tid >> 4;
#pragma unroll
        for (int cc = 0; cc < 4; ++cc) {
            red[0][gr][c4 * 4 + cc] = ls[cc];
            red[1][gr][c4 * 4 + cc] = lq[cc];
        }
        __syncthreads();
        if (tid < 64) {
            float s = 0.0f, q = 0.0f;
            for (int g2 = 0; g2 < 16; ++g2) { s += red[0][g2][tid]; q += red[1][g2][tid]; }
            atomicAdd(&gstats[640 + tid], s);
            atomicAdd(&gstats[704 + tid], q);
        }
    }
    grid.sync();

    if (blockIdx.x == 0 && tid < 128)
        finalize2_body(tid, gstats, g_c22, beta_c22, g_c32, beta_c32, scales);
    grid.sync();

    // phase D: out = tanh(edge + BN22(u) + BN32(agg)); u lives in out
    {
        const int c4 = tid & 15;
        float su[4], hu[4], sa[4], ha[4];
#pragma unroll
        for (int cc = 0; cc < 4; ++cc) {
            const int col = c4 * 4 + cc;
            su[cc] = scales[512 + col]; hu[cc] = scales[576 + col];
            sa[cc] = scales[640 + col]; ha[cc] = scales[704 + col];
        }
        const long total = (long)NEDGE * 16;
        const long stride = (long)gridDim.x * 256;
        for (long idx = (long)blockIdx.x * 256 + tid; idx < total; idx += stride) {
            const int row = (int)(idx >> 4);
            const size_t base = (size_t)row * 64 + c4 * 4;
            const float4 e = *reinterpret_cast<const float4*>(&edge[base]);
            const float4 u = *reinterpret_cast<const float4*>(&out[base]);
            const float4 a = *reinterpret_cast<const float4*>(&agg[base]);
            float4 o;
            o.x = tanh_f(e.x + u.x * su[0] + hu[0] + a.x * sa[0] + ha[0]);
            o.y = tanh_f(e.y + u.y * su[1] + hu[1] + a.y * sa[1] + ha[1]);
            o.z = tanh_f(e.z + u.z * su[2] + hu[2] + a.z * sa[2] + ha[2]);
            o.w = tanh_f(e.w + u.w * su[3] + hu[3] + a.w * sa[3] + ha[3]);
            *reinterpret_cast<float4*>(&out[base]) = o;
        }
    }
}

// ---------------------------------------------------------------------------
// r8 fallback kernels (wrap the same tile bodies)
// ---------------------------------------------------------------------------
template <int TERMS>
__global__ __launch_bounds__(256) void k_gemm_c3_sep(
    const float* node, const float* edge,
    const int* idx_i, const int* idx_j, const int* idx_k,
    const int* idx_ji, const int* idx_kj, const float* W3,
    float* gstats, const float* scales, float* agg)
{
    __shared__ unsigned smem[4 * 2560 + 256];
    c3_tile<TERMS>(blockIdx.x, node, edge, idx_i, idx_j, idx_k, idx_ji,
                   idx_kj, W3, gstats, scales, agg, smem);
}

template <int TERMS>
__global__ __launch_bounds__(256) void k_gemm_c2_sep(
    const float* node, const int* vi, const int* vj, const float* W2,
    float* gstats, const float* scales, float* uout)
{
    __shared__ unsigned smem[4 * 2560 + 256];
    c2_tile<TERMS>(blockIdx.x, node, vi, vj, W2, gstats, scales, uout, smem);
}

__global__ void k_finalize1(const float* gstats, const float* g_c2,
                            const float* beta_c2, const float* g_c3,
                            const float* beta_c3, float* scales)
{
    finalize1_body(threadIdx.x, gstats, g_c2, beta_c2, g_c3, beta_c3, scales);
}

__global__ void k_finalize2(const float* gstats, const float* g_c22,
                            const float* beta_c22, const float* g_c32,
                            const float* beta_c32, float* scales)
{
    finalize2_body(threadIdx.x, gstats, g_c22, beta_c22, g_c32, beta_c32, scales);
}

__global__ __launch_bounds__(256) void k_stats_agg(
    const float* __restrict__ agg, float* __restrict__ gstats)
{
    const int tid = threadIdx.x;
    const int c4 = tid & 15;
    float ls[4] = {0, 0, 0, 0}, lq[4] = {0, 0, 0, 0};
    const long total = (long)NEDGE * 16;
    const long stride = (long)gridDim.x * blockDim.x;
    for (long idx = (long)blockIdx.x * blockDim.x + tid; idx < total; idx += stride) {
        const int row = (int)(idx >> 4);
        const float4 a = *reinterpret_cast<const float4*>(&agg[(size_t)row * 64 + c4 * 4]);
        ls[0] += a.x; lq[0] += a.x * a.x;
        ls[1] += a.y; lq[1] += a.y * a.y;
        ls[2] += a.z; lq[2] += a.z * a.z;
        ls[3] += a.w; lq[3] += a.w * a.w;
    }
    __shared__ float red[2][16][68];
    const int gr = tid >> 4;
#pragma unroll
    for (int cc = 0; cc < 4; ++cc) {
        red[0][gr][c4 * 4 + cc] = ls[cc];
        red[1][gr][c4 * 4 + cc] = lq[cc];
    }
    __syncthreads();
    if (tid < 64) {
        float s = 0.0f, q = 0.0f;
        for (int g2 = 0; g2 < 16; ++g2) { s += red[0][g2][tid]; q += red[1][g2][tid]; }
        atomicAdd(&gstats[640 + tid], s);
        atomicAdd(&gstats[704 + tid], q);
    }
}

__global__ __launch_bounds__(256) void k_final(
    const float* __restrict__ edge, const float* __restrict__ agg,
    const float* __restrict__ scales, float* __restrict__ out)
{
    const int tid = threadIdx.x;
    const int c4 = tid & 15;
    float su[4], hu[4], sa[4], ha[4];
#pragma unroll
    for (int cc = 0; cc < 4; ++cc) {
        const int col = c4 * 4 + cc;
        su[cc] = scales[512 + col]; hu[cc] = scales[576 + col];
        sa[cc] = scales[640 + col]; ha[cc] = scales[704 + col];
    }
    const long total = (long)NEDGE * 16;
    const long stride = (long)gridDim.x * blockDim.x;
    for (long idx = (long)blockIdx.x * blockDim.x + tid; idx < total; idx += stride) {
        const int row = (int)(idx >> 4);
        const size_t base = (size_t)row * 64 + c4 * 4;
        const float4 e = *reinterpret_cast<const float4*>(&edge[base]);
        const float4 u = *reinterpret_cast<const float4*>(&out[base]);
        const float4 a = *reinterpret_cast<const float4*>(&agg[base]);
        float4 o;
        o.x = tanh_f(e.x + u.x * su[0] + hu[0] + a.x * sa[0] + ha[0]);
        o.y = tanh_f(e.y + u.y * su[1] + hu[1] + a.y * sa[1] + ha[1]);
        o.z = tanh_f(e.z + u.z * su[2] + hu[2] + a.z * sa[2] + ha[2]);
        o.w = tanh_f(e.w + u.w * su[3] + hu[3] + a.w * sa[3] + ha[3]);
        *reinterpret_cast<float4*>(&out[base]) = o;
    }
}

// ---------------------------------------------------------------------------
extern "C" void kernel_launch(void* const* d_in, const int* in_sizes, int n_in,
                              void* d_out, int out_size, void* d_ws, size_t ws_size,
                              hipStream_t stream)
{
    (void)in_sizes; (void)n_in; (void)out_size; (void)ws_size;
    const float* node   = (const float*)d_in[0];
    const float* edge   = (const float*)d_in[1];
    const int*   vi     = (const int*)d_in[2];
    const int*   vj     = (const int*)d_in[3];
    const int*   idx_i  = (const int*)d_in[4];
    const int*   idx_j  = (const int*)d_in[5];
    const int*   idx_k  = (const int*)d_in[6];
    const int*   idx_ji = (const int*)d_in[7];
    const int*   idx_kj = (const int*)d_in[8];
    const float* W2     = (const float*)d_in[9];
    const float* W3     = (const float*)d_in[11];
    const float* g_c2    = (const float*)d_in[13];
    const float* beta_c2 = (const float*)d_in[14];
    const float* g_c3    = (const float*)d_in[15];
    const float* beta_c3 = (const float*)d_in[16];
    const float* g_c22    = (const float*)d_in[17];
    const float* beta_c22 = (const float*)d_in[18];
    const float* g_c32    = (const float*)d_in[19];
    const float* beta_c32 = (const float*)d_in[20];
    float* out = (float*)d_out;

    float* ws     = (float*)d_ws;
    float* gstats = ws;                        // 768 floats
    float* scales = ws + 768;                  // 768 floats
    float* agg    = ws + 1536;                 // E*64 floats (~51.2 MB)

    hipMemsetAsync(gstats, 0, 768 * sizeof(float), stream);
    hipMemsetAsync(agg, 0, (size_t)NEDGE * 64 * sizeof(float), stream);

    // cooperative capability + resident-grid sizing (queries only; capture-safe)
    int coop = 0, nb = 0, ncu = 0, dev = 0;
    hipGetDevice(&dev);
    hipDeviceGetAttribute(&coop, hipDeviceAttributeCooperativeLaunch, dev);
    hipDeviceGetAttribute(&ncu, hipDeviceAttributeMultiprocessorCount, dev);
    hipOccupancyMaxActiveBlocksPerMultiprocessor(&nb, k_mega, 256, 0);

    bool done = false;
    if (coop && nb > 0 && ncu > 0) {
        int grid = nb * ncu;
        if (grid > NB3 + NB2) grid = NB3 + NB2;
        void* args[] = {
            (void*)&node, (void*)&edge, (void*)&vi, (void*)&vj,
            (void*)&idx_i, (void*)&idx_j, (void*)&idx_k, (void*)&idx_ji,
            (void*)&idx_kj, (void*)&W2, (void*)&W3,
            (void*)&g_c2, (void*)&beta_c2, (void*)&g_c3, (void*)&beta_c3,
            (void*)&g_c22, (void*)&beta_c22, (void*)&g_c32, (void*)&beta_c32,
            (void*)&gstats, (void*)&scales, (void*)&agg, (void*)&out };
        hipError_t err = hipLaunchCooperativeKernel(
            (const void*)k_mega, dim3(grid), dim3(256), args, 0, stream);
        done = (err == hipSuccess);
    }

    if (!done) {
        // r8 fallback path (791 us proven)
        k_gemm_c2_sep<1><<<NB2, 256, 0, stream>>>(
            node, vi, vj, W2, gstats, nullptr, nullptr);
        k_gemm_c3_sep<1><<<NB3, 256, 0, stream>>>(
            node, edge, idx_i, idx_j, idx_k, idx_ji, idx_kj, W3,
            gstats, nullptr, nullptr);
        k_finalize1<<<1, 256, 0, stream>>>(gstats, g_c2, beta_c2, g_c3, beta_c3, scales);
        k_gemm_c2_sep<3><<<NB2, 256, 0, stream>>>(
            node, vi, vj, W2, gstats, scales, out);
        k_gemm_c3_sep<3><<<NB3, 256, 0, stream>>>(
            node, edge, idx_i, idx_j, idx_k, idx_ji, idx_kj, W3,
            gstats, scales, agg);
        k_stats_agg<<<3072, 256, 0, stream>>>(agg, gstats);
        k_finalize2<<<1, 128, 0, stream>>>(gstats, g_c22, beta_c22, g_c32, beta_c32, scales);
        k_final<<<3072, 256, 0, stream>>>(edge, agg, scales, out);
    }
}

// Round 11
// 794.079 us; speedup vs baseline: 1.5079x; 1.5079x over previous
//
#include <hip/hip_runtime.h>
#include <cstdint>

#define HN 64
#define HE 64
#define NNODE 50000
#define NEDGE 200000
#define NTRIP 600000
#define EPSBN 1e-5f

// gstats layout (floats): c2_sum(128) c2_sq(128) c3_sum(128) c3_sq(128)
//                         u_sum(64) u_sq(64) agg_sum(64) agg_sq(64)   = 768
// scales layout (floats): c2_scale(128) c2_shift(128) c3_scale(128) c3_shift(128)
//                         u_scale(64) u_shift(64) agg_scale(64) agg_shift(64) = 768

typedef __attribute__((ext_vector_type(8))) short short8;
typedef __attribute__((ext_vector_type(4))) float f32x4;

__device__ __forceinline__ float sigmoid_f(float x) {
    return 1.0f / (1.0f + __expf(-x));
}
__device__ __forceinline__ float tanh_f(float x) {
    return 1.0f - 2.0f / (__expf(2.0f * x) + 1.0f);
}

__device__ __forceinline__ short8 as_s8(uint4 v) {
    union { uint4 u; short8 s; } c; c.u = v; return c.s;
}

// convert 16 fp32 -> 8 packed-u32 of bf16-hi (and optionally bf16-lo), write to LDS
__device__ __forceinline__ void cvt_store16(
    float4 x0, float4 x1, float4 x2, float4 x3,
    unsigned int* __restrict__ dhi, unsigned int* __restrict__ dlo, bool do_lo)
{
    float xv[16] = {x0.x, x0.y, x0.z, x0.w, x1.x, x1.y, x1.z, x1.w,
                    x2.x, x2.y, x2.z, x2.w, x3.x, x3.y, x3.z, x3.w};
    unsigned hu[16];
#pragma unroll
    for (int e = 0; e < 16; ++e) hu[e] = __float_as_uint(xv[e]) >> 16;  // truncate split
#pragma unroll
    for (int m = 0; m < 8; ++m) dhi[m] = (hu[2 * m + 1] << 16) | hu[2 * m];
    if (do_lo) {
        unsigned lu[16];
#pragma unroll
        for (int e = 0; e < 16; ++e) {
            const float hf = __uint_as_float(hu[e] << 16);
            lu[e] = __float_as_uint(xv[e] - hf) >> 16;  // exact residual, trunc to bf16
        }
#pragma unroll
        for (int m = 0; m < 8; ++m) dlo[m] = (lu[2 * m + 1] << 16) | lu[2 * m];
    }
}

// ---------------------------------------------------------------------------
// c3 GEMM via bf16 MFMA, split precision — EXACT round-0 kernel (fastest
// measured: MODE0=231us, MODE2~225us). Rounds 1-7 tried barrier relaxation,
// prefetch, pre-converted planes, no-LDS direct, big-batch B: all 230-340us.
// Rounds 9-10: block-ID fusion and cooperative phase-fusion both regressed.
// Do not touch without a within-probe A/B.
// ---------------------------------------------------------------------------
template <int MODE>
__global__ __launch_bounds__(256) void k_gemm_c3_mfma(
    const float* __restrict__ node, const float* __restrict__ edge,
    const int* __restrict__ idx_i, const int* __restrict__ idx_j,
    const int* __restrict__ idx_k, const int* __restrict__ idx_ji,
    const int* __restrict__ idx_kj, const float* __restrict__ W3,
    float* __restrict__ gsum, float* __restrict__ gsq,
    const float* __restrict__ scales, float* __restrict__ agg)
{
    constexpr int TERMS = (MODE == 0) ? 1 : 3;
    constexpr int LDA = 20;                    // u32 stride per row (16 + pad, 16B-aligned)
    constexpr int PLANE = 128 * LDA;           // one hi or lo plane

    __shared__ unsigned int sA[PLANE * ((TERMS == 1) ? 1 : 2)];
    __shared__ unsigned int sB[PLANE * ((TERMS == 1) ? 1 : 2)];
    __shared__ float sstat[256];

    const int tid = threadIdx.x;
    const int lane = tid & 63;
    const int w = tid >> 6;       // wave 0..3
    const int quad = lane >> 4;   // 0..3
    const int l16 = lane & 15;
    const int bm = blockIdx.x * 128;

    // staging role: 2 threads per tile-row, 16 elements each
    const int srow = tid >> 1;
    const int shalf = tid & 1;
    int g = bm + srow;
    if (g >= NTRIP) g = NTRIP - 1;
    const int r0 = idx_i[g], r1 = idx_j[g], r2 = idx_k[g];
    const int r3 = idx_ji[g], r4 = idx_kj[g];

    f32x4 acc[2][8];
#pragma unroll
    for (int mi = 0; mi < 2; ++mi)
#pragma unroll
        for (int ni = 0; ni < 8; ++ni) acc[mi][ni] = (f32x4){0.f, 0.f, 0.f, 0.f};

    for (int s = 0; s < 10; ++s) {
        const int seg = s >> 1;
        const int kin = (s & 1) * 32;
        const float* src;
        switch (seg) {
            case 0: src = node + (size_t)r0 * 64; break;
            case 1: src = node + (size_t)r1 * 64; break;
            case 2: src = node + (size_t)r2 * 64; break;
            case 3: src = edge + (size_t)r3 * 64; break;
            default: src = edge + (size_t)r4 * 64; break;
        }
        const float4* pa = reinterpret_cast<const float4*>(src + kin + shalf * 16);
        float4 a0 = pa[0], a1 = pa[1], a2 = pa[2], a3 = pa[3];
        const float4* pb = reinterpret_cast<const float4*>(
            W3 + (size_t)srow * 320 + seg * 64 + kin + shalf * 16);
        float4 b0 = pb[0], b1 = pb[1], b2 = pb[2], b3 = pb[3];

        __syncthreads();  // prior iteration's fragment reads done
        {
            unsigned int* dA = sA + srow * LDA + shalf * 8;
            unsigned int* dB = sB + srow * LDA + shalf * 8;
            cvt_store16(a0, a1, a2, a3, dA, dA + PLANE, TERMS == 3);
            cvt_store16(b0, b1, b2, b3, dB, dB + PLANE, TERMS == 3);
        }
        __syncthreads();

        // fragments: A rows = w*32 + mi*16 + l16 ; k-chunk = quad*4 u32
        uint4 ahi[2], alo[2];
#pragma unroll
        for (int mi = 0; mi < 2; ++mi) {
            const int abase = (w * 32 + mi * 16 + l16) * LDA + quad * 4;
            ahi[mi] = *reinterpret_cast<const uint4*>(&sA[abase]);
            if (TERMS == 3) alo[mi] = *reinterpret_cast<const uint4*>(&sA[PLANE + abase]);
        }
#pragma unroll
        for (int ni = 0; ni < 8; ++ni) {
            const int bbase = (ni * 16 + l16) * LDA + quad * 4;
            const uint4 bhi = *reinterpret_cast<const uint4*>(&sB[bbase]);
#pragma unroll
            for (int mi = 0; mi < 2; ++mi)
                acc[mi][ni] = __builtin_amdgcn_mfma_f32_16x16x32_bf16(
                    as_s8(ahi[mi]), as_s8(bhi), acc[mi][ni], 0, 0, 0);
            if (TERMS == 3) {
                const uint4 blo = *reinterpret_cast<const uint4*>(&sB[PLANE + bbase]);
#pragma unroll
                for (int mi = 0; mi < 2; ++mi) {
                    acc[mi][ni] = __builtin_amdgcn_mfma_f32_16x16x32_bf16(
                        as_s8(ahi[mi]), as_s8(blo), acc[mi][ni], 0, 0, 0);
                    acc[mi][ni] = __builtin_amdgcn_mfma_f32_16x16x32_bf16(
                        as_s8(alo[mi]), as_s8(bhi), acc[mi][ni], 0, 0, 0);
                }
            }
        }
    }

    // C/D layout: col = ni*16 + l16, row = w*32 + mi*16 + quad*4 + reg
    if (MODE == 0) {
        __syncthreads();
        sstat[tid] = 0.0f;
        __syncthreads();
#pragma unroll
        for (int ni = 0; ni < 8; ++ni) {
            const int col = ni * 16 + l16;
            float s = 0.0f, q = 0.0f;
#pragma unroll
            for (int mi = 0; mi < 2; ++mi)
#pragma unroll
                for (int reg = 0; reg < 4; ++reg) {
                    const int grow = bm + w * 32 + mi * 16 + quad * 4 + reg;
                    if (grow < NTRIP) {
                        const float v = acc[mi][ni][reg];
                        s += v; q += v * v;
                    }
                }
            atomicAdd(&sstat[col], s);
            atomicAdd(&sstat[128 + col], q);
        }
        __syncthreads();
        if (tid < 128) {
            atomicAdd(&gsum[tid], sstat[tid]);
            atomicAdd(&gsq[tid], sstat[128 + tid]);
        }
    }

    if (MODE == 2) {
        float sf[4], hf[4], sc[4], hc[4];
#pragma unroll
        for (int ni = 0; ni < 4; ++ni) {
            const int col = ni * 16 + l16;
            sf[ni] = scales[256 + col];      hf[ni] = scales[384 + col];
            sc[ni] = scales[256 + 64 + col]; hc[ni] = scales[384 + 64 + col];
        }
#pragma unroll
        for (int mi = 0; mi < 2; ++mi)
#pragma unroll
            for (int reg = 0; reg < 4; ++reg) {
                const int grow = bm + w * 32 + mi * 16 + quad * 4 + reg;
                if (grow < NTRIP) {
                    const int e = idx_ji[grow];
                    float* dst = &agg[(size_t)e * 64 + l16];
#pragma unroll
                    for (int ni = 0; ni < 4; ++ni) {
                        const float fv = acc[mi][ni][reg] * sf[ni] + hf[ni];
                        const float cv = acc[mi][ni + 4][reg] * sc[ni] + hc[ni];
                        atomicAdd(dst + ni * 16, sigmoid_f(fv) * tanh_f(cv));
                    }
                }
            }
    }
}

// ---------------------------------------------------------------------------
// c2 GEMM via bf16 MFMA: C(E,128) = (node[vi]*node[vj]) @ W2^T, K=64.
// Same proven structure as the r0 c3 kernel (128 rows/block, 4 waves, 2x8
// frags), 2 k-chunks of 32. Replaced the fp32 VALU version (r8: -47us total).
// MODE 0: 1-term hi, column stats. MODE 2: 3-term, BN+gate -> uout + u stats.
// ---------------------------------------------------------------------------
template <int MODE>
__global__ __launch_bounds__(256) void k_gemm_c2_m(
    const float* __restrict__ node, const int* __restrict__ vi,
    const int* __restrict__ vj, const float* __restrict__ W2,
    float* __restrict__ gsum, float* __restrict__ gsq,
    const float* __restrict__ scales, float* __restrict__ uout,
    float* __restrict__ usum, float* __restrict__ usq)
{
    constexpr int TERMS = (MODE == 0) ? 1 : 3;
    constexpr int LDA = 20;
    constexpr int PLANE = 128 * LDA;

    __shared__ unsigned int sA[PLANE * ((TERMS == 1) ? 1 : 2)];
    __shared__ unsigned int sB[PLANE * ((TERMS == 1) ? 1 : 2)];

    const int tid = threadIdx.x;
    const int lane = tid & 63;
    const int w = tid >> 6;
    const int quad = lane >> 4;
    const int l16 = lane & 15;
    const int bm = blockIdx.x * 128;

    const int srow = tid >> 1;
    const int shalf = tid & 1;
    int g = bm + srow;
    if (g >= NEDGE) g = NEDGE - 1;
    const int r0 = vi[g], r1 = vj[g];

    f32x4 acc[2][8];
#pragma unroll
    for (int mi = 0; mi < 2; ++mi)
#pragma unroll
        for (int ni = 0; ni < 8; ++ni) acc[mi][ni] = (f32x4){0.f, 0.f, 0.f, 0.f};

    for (int s = 0; s < 2; ++s) {
        const int kin = s * 32;
        const float4* pa = reinterpret_cast<const float4*>(
            node + (size_t)r0 * 64 + kin + shalf * 16);
        const float4* pc = reinterpret_cast<const float4*>(
            node + (size_t)r1 * 64 + kin + shalf * 16);
        float4 a0 = pa[0], a1 = pa[1], a2 = pa[2], a3 = pa[3];
        float4 c0 = pc[0], c1 = pc[1], c2 = pc[2], c3 = pc[3];
        // elementwise product in fp32 (exact), then split in cvt_store16
        float4 m0 = make_float4(a0.x*c0.x, a0.y*c0.y, a0.z*c0.z, a0.w*c0.w);
        float4 m1 = make_float4(a1.x*c1.x, a1.y*c1.y, a1.z*c1.z, a1.w*c1.w);
        float4 m2 = make_float4(a2.x*c2.x, a2.y*c2.y, a2.z*c2.z, a2.w*c2.w);
        float4 m3 = make_float4(a3.x*c3.x, a3.y*c3.y, a3.z*c3.z, a3.w*c3.w);
        const float4* pw = reinterpret_cast<const float4*>(
            W2 + (size_t)srow * 64 + kin + shalf * 16);
        float4 w0 = pw[0], w1 = pw[1], w2 = pw[2], w3 = pw[3];

        __syncthreads();
        {
            unsigned int* dA = sA + srow * LDA + shalf * 8;
            unsigned int* dB = sB + srow * LDA + shalf * 8;
            cvt_store16(m0, m1, m2, m3, dA, dA + PLANE, TERMS == 3);
            cvt_store16(w0, w1, w2, w3, dB, dB + PLANE, TERMS == 3);
        }
        __syncthreads();

        uint4 ahi[2], alo[2];
#pragma unroll
        for (int mi = 0; mi < 2; ++mi) {
            const int abase = (w * 32 + mi * 16 + l16) * LDA + quad * 4;
            ahi[mi] = *reinterpret_cast<const uint4*>(&sA[abase]);
            if (TERMS == 3) alo[mi] = *reinterpret_cast<const uint4*>(&sA[PLANE + abase]);
        }
#pragma unroll
        for (int ni = 0; ni < 8; ++ni) {
            const int bbase = (ni * 16 + l16) * LDA + quad * 4;
            const uint4 bhi = *reinterpret_cast<const uint4*>(&sB[bbase]);
#pragma unroll
            for (int mi = 0; mi < 2; ++mi)
                acc[mi][ni] = __builtin_amdgcn_mfma_f32_16x16x32_bf16(
                    as_s8(ahi[mi]), as_s8(bhi), acc[mi][ni], 0, 0, 0);
            if (TERMS == 3) {
                const uint4 blo = *reinterpret_cast<const uint4*>(&sB[PLANE + bbase]);
#pragma unroll
                for (int mi = 0; mi < 2; ++mi) {
                    acc[mi][ni] = __builtin_amdgcn_mfma_f32_16x16x32_bf16(
                        as_s8(ahi[mi]), as_s8(blo), acc[mi][ni], 0, 0, 0);
                    acc[mi][ni] = __builtin_amdgcn_mfma_f32_16x16x32_bf16(
                        as_s8(alo[mi]), as_s8(bhi), acc[mi][ni], 0, 0, 0);
                }
            }
        }
    }

    // C/D layout: col = ni*16 + l16, row = w*32 + mi*16 + quad*4 + reg
    if constexpr (MODE == 0) {
        float* sstat = reinterpret_cast<float*>(sA);   // sA dead after loop
        __syncthreads();
        sstat[tid] = 0.0f;
        __syncthreads();
#pragma unroll
        for (int ni = 0; ni < 8; ++ni) {
            const int col = ni * 16 + l16;
            float s = 0.0f, q = 0.0f;
#pragma unroll
            for (int mi = 0; mi < 2; ++mi)
#pragma unroll
                for (int reg = 0; reg < 4; ++reg) {
                    const int grow = bm + w * 32 + mi * 16 + quad * 4 + reg;
                    if (grow < NEDGE) {
                        const float v = acc[mi][ni][reg];
                        s += v; q += v * v;
                    }
                }
            atomicAdd(&sstat[col], s);
            atomicAdd(&sstat[128 + col], q);
        }
        __syncthreads();
        if (tid < 128) {
            atomicAdd(&gsum[tid], sstat[tid]);
            atomicAdd(&gsq[tid], sstat[128 + tid]);
        }
    }

    if constexpr (MODE == 2) {
        float sf[4], hf[4], sc[4], hc[4];
#pragma unroll
        for (int ni = 0; ni < 4; ++ni) {
            const int col = ni * 16 + l16;            // filter col; core = 64+col
            sf[ni] = scales[col];       hf[ni] = scales[128 + col];
            sc[ni] = scales[64 + col];  hc[ni] = scales[192 + col];
        }
        float lsum[4] = {0, 0, 0, 0}, lsq[4] = {0, 0, 0, 0};
#pragma unroll
        for (int mi = 0; mi < 2; ++mi)
#pragma unroll
            for (int reg = 0; reg < 4; ++reg) {
                const int grow = bm + w * 32 + mi * 16 + quad * 4 + reg;
                if (grow < NEDGE) {
#pragma unroll
                    for (int ni = 0; ni < 4; ++ni) {
                        const float f = acc[mi][ni][reg] * sf[ni] + hf[ni];
                        const float c = acc[mi][ni + 4][reg] * sc[ni] + hc[ni];
                        const float uv = sigmoid_f(f) * tanh_f(c);
                        uout[(size_t)grow * 64 + ni * 16 + l16] = uv;
                        lsum[ni] += uv; lsq[ni] += uv * uv;
                    }
                }
            }
        float* sstat = reinterpret_cast<float*>(sA);   // sA dead after loop
        __syncthreads();
        if (tid < 128) sstat[tid] = 0.0f;
        __syncthreads();
#pragma unroll
        for (int ni = 0; ni < 4; ++ni) {
            atomicAdd(&sstat[ni * 16 + l16], lsum[ni]);
            atomicAdd(&sstat[64 + ni * 16 + l16], lsq[ni]);
        }
        __syncthreads();
        if (tid < 64) {
            atomicAdd(&usum[tid], sstat[tid]);
            atomicAdd(&usq[tid], sstat[64 + tid]);
        }
    }
}

// ---------------------------------------------------------------------------
__global__ void k_finalize1(const float* __restrict__ gstats,
                            const float* __restrict__ g_c2, const float* __restrict__ beta_c2,
                            const float* __restrict__ g_c3, const float* __restrict__ beta_c3,
                            float* __restrict__ scales)
{
    const int t = threadIdx.x;
    if (t < 128) {
        const float inv = 1.0f / (float)NEDGE;
        const float mean = gstats[t] * inv;
        const float var = gstats[128 + t] * inv - mean * mean;
        const float sc = g_c2[t] * rsqrtf(var + EPSBN);
        scales[t] = sc;
        scales[128 + t] = beta_c2[t] - mean * sc;
    } else {
        const int c = t - 128;
        const float inv = 1.0f / (float)NTRIP;
        const float mean = gstats[256 + c] * inv;
        const float var = gstats[384 + c] * inv - mean * mean;
        const float sc = g_c3[c] * rsqrtf(var + EPSBN);
        scales[256 + c] = sc;
        scales[384 + c] = beta_c3[c] - mean * sc;
    }
}

__global__ void k_finalize2(const float* __restrict__ gstats,
                            const float* __restrict__ g_c22, const float* __restrict__ beta_c22,
                            const float* __restrict__ g_c32, const float* __restrict__ beta_c32,
                            float* __restrict__ scales)
{
    const int t = threadIdx.x;
    const float inv = 1.0f / (float)NEDGE;
    if (t < 64) {
        const float mean = gstats[512 + t] * inv;
        const float var = gstats[576 + t] * inv - mean * mean;
        const float sc = g_c22[t] * rsqrtf(var + EPSBN);
        scales[512 + t] = sc;
        scales[576 + t] = beta_c22[t] - mean * sc;
    } else {
        const int c = t - 64;
        const float mean = gstats[640 + c] * inv;
        const float var = gstats[704 + c] * inv - mean * mean;
        const float sc = g_c32[c] * rsqrtf(var + EPSBN);
        scales[640 + c] = sc;
        scales[704 + c] = beta_c32[c] - mean * sc;
    }
}

// ---------------------------------------------------------------------------
__global__ __launch_bounds__(256) void k_stats_agg(
    const float* __restrict__ agg, float* __restrict__ gstats)
{
    const int tid = threadIdx.x;
    const int c4 = tid & 15;
    float ls[4] = {0, 0, 0, 0}, lq[4] = {0, 0, 0, 0};
    const long total = (long)NEDGE * 16;
    const long stride = (long)gridDim.x * blockDim.x;
    for (long idx = (long)blockIdx.x * blockDim.x + tid; idx < total; idx += stride) {
        const int row = (int)(idx >> 4);
        const float4 a = *reinterpret_cast<const float4*>(&agg[(size_t)row * 64 + c4 * 4]);
        ls[0] += a.x; lq[0] += a.x * a.x;
        ls[1] += a.y; lq[1] += a.y * a.y;
        ls[2] += a.z; lq[2] += a.z * a.z;
        ls[3] += a.w; lq[3] += a.w * a.w;
    }
    __shared__ float red[2][16][68];
    const int gr = tid >> 4;
#pragma unroll
    for (int cc = 0; cc < 4; ++cc) {
        red[0][gr][c4 * 4 + cc] = ls[cc];
        red[1][gr][c4 * 4 + cc] = lq[cc];
    }
    __syncthreads();
    if (tid < 64) {
        float s = 0.0f, q = 0.0f;
        for (int g2 = 0; g2 < 16; ++g2) { s += red[0][g2][tid]; q += red[1][g2][tid]; }
        atomicAdd(&gstats[640 + tid], s);
        atomicAdd(&gstats[704 + tid], q);
    }
}

// ---------------------------------------------------------------------------
// out = tanh(edge + BN22(u) + BN32(agg));  u lives in d_out, overwritten here
// ---------------------------------------------------------------------------
__global__ __launch_bounds__(256) void k_final(
    const float* __restrict__ edge, const float* __restrict__ agg,
    const float* __restrict__ scales, float* __restrict__ out)
{
    const int tid = threadIdx.x;
    const int c4 = tid & 15;
    float su[4], hu[4], sa[4], ha[4];
#pragma unroll
    for (int cc = 0; cc < 4; ++cc) {
        const int col = c4 * 4 + cc;
        su[cc] = scales[512 + col]; hu[cc] = scales[576 + col];
        sa[cc] = scales[640 + col]; ha[cc] = scales[704 + col];
    }
    const long total = (long)NEDGE * 16;
    const long stride = (long)gridDim.x * blockDim.x;
    for (long idx = (long)blockIdx.x * blockDim.x + tid; idx < total; idx += stride) {
        const int row = (int)(idx >> 4);
        const size_t base = (size_t)row * 64 + c4 * 4;
        const float4 e = *reinterpret_cast<const float4*>(&edge[base]);
        const float4 u = *reinterpret_cast<const float4*>(&out[base]);
        const float4 a = *reinterpret_cast<const float4*>(&agg[base]);
        float4 o;
        o.x = tanh_f(e.x + u.x * su[0] + hu[0] + a.x * sa[0] + ha[0]);
        o.y = tanh_f(e.y + u.y * su[1] + hu[1] + a.y * sa[1] + ha[1]);
        o.z = tanh_f(e.z + u.z * su[2] + hu[2] + a.z * sa[2] + ha[2]);
        o.w = tanh_f(e.w + u.w * su[3] + hu[3] + a.w * sa[3] + ha[3]);
        *reinterpret_cast<float4*>(&out[base]) = o;
    }
}

// ---------------------------------------------------------------------------
extern "C" void kernel_launch(void* const* d_in, const int* in_sizes, int n_in,
                              void* d_out, int out_size, void* d_ws, size_t ws_size,
                              hipStream_t stream)
{
    (void)in_sizes; (void)n_in; (void)out_size; (void)ws_size;
    const float* node   = (const float*)d_in[0];
    const float* edge   = (const float*)d_in[1];
    const int*   vi     = (const int*)d_in[2];
    const int*   vj     = (const int*)d_in[3];
    const int*   idx_i  = (const int*)d_in[4];
    const int*   idx_j  = (const int*)d_in[5];
    const int*   idx_k  = (const int*)d_in[6];
    const int*   idx_ji = (const int*)d_in[7];
    const int*   idx_kj = (const int*)d_in[8];
    const float* W2     = (const float*)d_in[9];
    // d_in[10] = b2: cancels inside BN (mean subtraction)
    const float* W3     = (const float*)d_in[11];
    // d_in[12] = b3: cancels inside BN
    const float* g_c2    = (const float*)d_in[13];
    const float* beta_c2 = (const float*)d_in[14];
    const float* g_c3    = (const float*)d_in[15];
    const float* beta_c3 = (const float*)d_in[16];
    const float* g_c22    = (const float*)d_in[17];
    const float* beta_c22 = (const float*)d_in[18];
    const float* g_c32    = (const float*)d_in[19];
    const float* beta_c32 = (const float*)d_in[20];
    float* out = (float*)d_out;

    float* ws     = (float*)d_ws;
    float* gstats = ws;                        // 768 floats
    float* scales = ws + 768;                  // 768 floats
    float* agg    = ws + 1536;                 // E*64 floats (~51.2 MB total)

    hipMemsetAsync(gstats, 0, 768 * sizeof(float), stream);
    hipMemsetAsync(agg, 0, (size_t)NEDGE * 64 * sizeof(float), stream);

    const int grid_c2 = (NEDGE + 127) / 128;
    const int grid_c3 = (NTRIP + 127) / 128;

    // pass 1: column stats (both GEMMs via 1-term bf16 MFMA)
    k_gemm_c2_m<0><<<grid_c2, 256, 0, stream>>>(
        node, vi, vj, W2, gstats + 0, gstats + 128, nullptr, nullptr, nullptr, nullptr);
    k_gemm_c3_mfma<0><<<grid_c3, 256, 0, stream>>>(
        node, edge, idx_i, idx_j, idx_k, idx_ji, idx_kj, W3,
        gstats + 256, gstats + 384, nullptr, nullptr);
    k_finalize1<<<1, 256, 0, stream>>>(gstats, g_c2, beta_c2, g_c3, beta_c3, scales);

    // pass 2: apply BN + gates; u -> d_out (scratch), msg -> agg (atomics)
    // both via 3-term split bf16 MFMA (ah*bh + ah*bl + al*bh, err ~2^-16)
    k_gemm_c2_m<2><<<grid_c2, 256, 0, stream>>>(
        node, vi, vj, W2, nullptr, nullptr, scales, out, gstats + 512, gstats + 576);
    k_gemm_c3_mfma<2><<<grid_c3, 256, 0, stream>>>(
        node, edge, idx_i, idx_j, idx_k, idx_ji, idx_kj, W3,
        nullptr, nullptr, scales, agg);

    k_stats_agg<<<3072, 256, 0, stream>>>(agg, gstats);
    k_finalize2<<<1, 128, 0, stream>>>(gstats, g_c22, beta_c22, g_c32, beta_c32, scales);
    k_final<<<3072, 256, 0, stream>>>(edge, agg, scales, out);
}